// Round 13
// baseline (1267.928 us; speedup 1.0000x reference)
//
#include <hip/hip_runtime.h>
#include <hip/hip_bf16.h>

// Problem constants
#define Bx 32
#define Nx 512
#define Dx 512
#define Hx 8
#define DKx 64
#define FFx 2048
#define TOK (Bx * Nx)          // 16384 tokens
#define EPSx 1e-5f

typedef float  f32x4  __attribute__((ext_vector_type(4)));
typedef _Float16 hfrag8 __attribute__((ext_vector_type(8)));
typedef _Float16 h4     __attribute__((ext_vector_type(4)));
typedef _Float16 h2     __attribute__((ext_vector_type(2)));

struct hf2 { _Float16 hi, lo; };
__device__ __forceinline__ hf2 split2h(float v) {
    _Float16 h = (_Float16)v;
    hf2 r; r.hi = h; r.lo = (_Float16)(v - (float)h);
    return r;
}

// Direct global->LDS DMA, 16B per lane. LDS dest = wave-uniform base + lane*16.
__device__ __forceinline__ void gl16(const void* g, void* l) {
    __builtin_amdgcn_global_load_lds(
        (const __attribute__((address_space(1))) unsigned int*)g,
        (__attribute__((address_space(3))) unsigned int*)l, 16, 0, 0);
}

// Swizzled byte offset within a plane for logical (row, 16B-slot q).
// Chunk-periodic (16 rows / 1KB): phys row = row>>1 (128B, bank-neutral);
// slot = (((row&1)<<2)|q) ^ ((row>>1)&7).
__device__ __forceinline__ int swzoff(int row, int q) {
    int p = row >> 1;
    int sl = ((row & 1) << 2) | q;
    int s = sl ^ (p & 7);
    return p * 128 + s * 16;
}

// ---------------------------------------------------------------------------
__device__ __forceinline__ float ldsel(const void* p32, const void* p16, size_t i, int f32) {
    return f32 ? ((const float*)p32)[i]
               : __bfloat162float(((const __hip_bfloat16*)p16)[i]);
}

__global__ void detect_kernel(const void* __restrict__ x, int* __restrict__ flag)
{
    if (threadIdx.x == 0 && blockIdx.x == 0) {
        const unsigned short* u = (const unsigned short*)x;
        int hits = 0;
        for (int i = 0; i < 256; ++i) {
            int e = (u[i] >> 7) & 0xFF;
            if (e >= 0x86) ++hits;
        }
        *flag = (hits > 8) ? 1 : 0;
    }
}

// ---------------------------------------------------------------------------
// Weight conversion: elementwise cast to single fp16 plane.
__global__ __launch_bounds__(256) void cvt_kernel(
    const void* __restrict__ W, _Float16* __restrict__ o, const int* __restrict__ dtp)
{
    const int f32 = *dtp;
    size_t idx = (size_t)blockIdx.x * 256 + threadIdx.x;
    o[idx] = (_Float16)ldsel(W, W, idx, f32);
}

// Weight conversion: transpose [R][C] -> [C][R] per matrix (blockIdx.z), fp16.
__global__ __launch_bounds__(256) void transpose_cvt_kernel(
    const void* __restrict__ W, _Float16* __restrict__ o,
    int R, int C, const int* __restrict__ dtp)
{
    const int f32 = *dtp;
    __shared__ float tile[64][65];
    const size_t mbase = (size_t)blockIdx.z * R * C;
    const int c0 = blockIdx.x * 64, r0 = blockIdx.y * 64;
    const int tc = threadIdx.x & 63, tg = threadIdx.x >> 6;
    #pragma unroll
    for (int i = 0; i < 16; ++i) {
        int r = tg * 16 + i;
        tile[r][tc] = ldsel(W, W, mbase + (size_t)(r0 + r) * C + c0 + tc, f32);
    }
    __syncthreads();
    #pragma unroll
    for (int i = 0; i < 16; ++i) {
        int cc = tg * 16 + i;
        o[mbase + (size_t)(c0 + cc) * R + r0 + tc] = (_Float16)tile[tc][cc];
    }
}

// ---------------------------------------------------------------------------
__global__ __launch_bounds__(256) void embed_kernel(
    const void* __restrict__ x, const void* __restrict__ We,
    const void* __restrict__ be, _Float16* __restrict__ hh, _Float16* __restrict__ hl,
    const int* __restrict__ dtp)
{
    const int f32 = *dtp;
    size_t idx = (size_t)blockIdx.x * 256 + threadIdx.x;
    int d = idx & (Dx - 1);
    size_t t = idx >> 9;
    float v = ldsel(x, x, t * 2, f32)     * ldsel(We, We, d * 2, f32) +
              ldsel(x, x, t * 2 + 1, f32) * ldsel(We, We, d * 2 + 1, f32) +
              ldsel(be, be, d, f32);
    hf2 s = split2h(v);
    hh[idx] = s.hi; hl[idx] = s.lo;
}

// ---------------------------------------------------------------------------
// MFMA GEMM, single-fp16 A and B planes. 128x256 tile, BK=32, 2x2 wave grid
// (each wave 64x128 out, acc[4][8]). 3-buffer LDS pipeline, ONE barrier per
// K-step (round-9 proven skeleton):
//   iter i: vmcnt(8) gate (stage-i landed) ; s_barrier ; stage step i+2 ;
//           ds_read buf(i%3)+32 MFMA ; lgkmcnt(0)
// Staging: wv0 -> A (8KB), wv1 -> B rows [0,128), wv2 -> B rows [128,256),
// 8 chunks each; wv3 load-free (role-split kept). 72 KB LDS -> 2 blk/CU.
// BN=256 halves B re-reads: staged bytes/FLOP drops 25-50% vs 128x128 —
// the staging-bandwidth currency this pipeline is bound by.
// STATS: fused per-column sum/sumsq partials (N==512), 64-row tile units.
// EPI: 1 +bias,relu ; 2 +bias(opt)+resid(fp16 planes).
// OHF: 0 fp32 out ; 1 fp16 single ; 2 packed {hi,lo} h2 out.
// ---------------------------------------------------------------------------
template <int EPI, int OHF, int STATS>
__global__ __launch_bounds__(256, 2) void gemm3(
    const _Float16* __restrict__ Ahg, const _Float16* __restrict__ Bg,
    const void* __restrict__ bias32, const void* __restrict__ bias16,
    const _Float16* __restrict__ residH, const _Float16* __restrict__ residL,
    void* __restrict__ outp, float* __restrict__ part,
    int M, int N, int K, const int* __restrict__ dtp)
{
    const int f32 = *dtp;
    __shared__ __align__(16) unsigned char lds[3][24576];   // A 8KB + B 16KB

    const int tid = threadIdx.x;
    // XCD-aware bijective swizzle (nwg % 8 == 0).
    const int gx = gridDim.x;
    const int nwg = gx * gridDim.y;
    int flat = blockIdx.y * gx + blockIdx.x;
    flat = (flat & 7) * (nwg >> 3) + (flat >> 3);
    const int bm = (flat / gx) * 128;
    const int bn = (flat % gx) * 256;

    const int lane = tid & 63, wv = tid >> 6;
    const int quad = lane >> 4, lrow = lane & 15;
    const int wm = (wv & 1) * 64, wn = (wv >> 1) * 128;

    f32x4 acc[4][8] = {};

    // staging lane-constants (inverse of the read swizzle)
    const int s2 = (lane & 7) ^ (lane >> 3);
    const int rl = 2 * (lane >> 3) + (s2 >> 2);   // row within 16-row chunk
    const int cl = (s2 & 3) * 8;                  // k element offset

    // wave -> staging role (wave-uniform); wv3 load-free
    const _Float16* wsrc = nullptr;
    int wrb = 0, wbase = 0;
    if (wv == 0)      { wsrc = Ahg; wrb = bm;       wbase = 0; }
    else if (wv == 1) { wsrc = Bg;  wrb = bn;       wbase = 8192; }
    else if (wv == 2) { wsrc = Bg;  wrb = bn + 128; wbase = 16384; }

    auto stage = [&](int step) {
        if (wsrc) {
            const int buf = step % 3;
            const int k0 = step << 5;
            const _Float16* s = wsrc + (size_t)(wrb + rl) * K + k0 + cl;
            #pragma unroll
            for (int ch = 0; ch < 8; ++ch)
                gl16(s + (size_t)(ch * 16) * K, &lds[buf][wbase + ch * 1024]);
        }
    };

    // precomputed fragment byte offsets (buffer-relative)
    int offA[4], offB[8];
    #pragma unroll
    for (int mt = 0; mt < 4; ++mt) offA[mt] = swzoff(wm + mt * 16 + lrow, quad);
    #pragma unroll
    for (int nt = 0; nt < 8; ++nt) offB[nt] = 8192 + swzoff(wn + nt * 16 + lrow, quad);

    const int NT = K >> 5;
    stage(0);
    stage(1);

    for (int i = 0; i < NT; ++i) {
        // wait for my stage-for-step-i only; stage(i+1) stays in flight
        if (i + 1 < NT) asm volatile("s_waitcnt vmcnt(8)" ::: "memory");
        else            asm volatile("s_waitcnt vmcnt(0)" ::: "memory");
        __builtin_amdgcn_sched_barrier(0);
        __builtin_amdgcn_s_barrier();   // step-i data resident; buf (i+2)%3 free
        __builtin_amdgcn_sched_barrier(0);

        if (i + 2 < NT) stage(i + 2);

        const unsigned char* bp = lds[i % 3];
        hfrag8 ah[4];
        #pragma unroll
        for (int mt = 0; mt < 4; ++mt)
            ah[mt] = *(const hfrag8*)(bp + offA[mt]);
        #pragma unroll
        for (int nt = 0; nt < 8; ++nt) {
            hfrag8 b = *(const hfrag8*)(bp + offB[nt]);
            #pragma unroll
            for (int mt = 0; mt < 4; ++mt)
                acc[mt][nt] = __builtin_amdgcn_mfma_f32_16x16x32_f16(ah[mt], b, acc[mt][nt], 0, 0, 0);
        }

        __builtin_amdgcn_sched_barrier(0);
        asm volatile("s_waitcnt lgkmcnt(0)" ::: "memory");   // my reads of buf i done
        __builtin_amdgcn_sched_barrier(0);
    }

    #pragma unroll
    for (int nt = 0; nt < 8; ++nt) {
        const int n = bn + wn + nt * 16 + lrow;
        float cs = 0.f, cq = 0.f;
        #pragma unroll
        for (int mt = 0; mt < 4; ++mt)
            #pragma unroll
            for (int reg = 0; reg < 4; ++reg) {
                int m = bm + wm + mt * 16 + quad * 4 + reg;
                float v = acc[mt][nt][reg];
                if constexpr (EPI == 1) { v += ldsel(bias32, bias16, n, f32); v = fmaxf(v, 0.f); }
                if constexpr (EPI == 2) {
                    if (bias32) v += ldsel(bias32, bias16, n, f32);
                    size_t ridx = (size_t)m * N + n;
                    v += (float)residH[ridx] + (float)residL[ridx];
                }
                size_t oidx = (size_t)m * N + n;
                if constexpr (OHF == 1) ((_Float16*)outp)[oidx] = (_Float16)v;
                else if constexpr (OHF == 2) {
                    hf2 s = split2h(v);
                    h2 pk; pk[0] = s.hi; pk[1] = s.lo;
                    ((h2*)outp)[oidx] = pk;           // single 4B store stream
                }
                else ((float*)outp)[oidx] = v;
                if constexpr (STATS) { cs += v; cq += v * v; }
            }
        if constexpr (STATS) {
            cs += __shfl_xor(cs, 16); cs += __shfl_xor(cs, 32);
            cq += __shfl_xor(cq, 16); cq += __shfl_xor(cq, 32);
            if (quad == 0) {
                float* pb = part + (size_t)(bm >> 6) * 1024;   // 64-row tile units
                atomicAdd(&pb[n], cs);          // 2 waves share a column
                atomicAdd(&pb[512 + n], cq);
            }
        }
    }
}

// ---------------------------------------------------------------------------
// Fused QKV projection: same 128x256 pipeline. N=1536, grid.x=6; each
// 256-tile lies within one of {Q,K,V} (sel boundary 512, 256 | 512).
// Q out fp16 hi/lo planes [H,B,N,DK]; K out single fp16; V fp16 [H,B,DK,N].
// ---------------------------------------------------------------------------
__global__ __launch_bounds__(256, 2) void qkv_mfma(
    const _Float16* __restrict__ Ahg,
    const _Float16* __restrict__ QT, const _Float16* __restrict__ KT,
    const _Float16* __restrict__ VT,
    _Float16* __restrict__ Qhg, _Float16* __restrict__ Qlg,
    _Float16* __restrict__ Khg, _Float16* __restrict__ Vo, int M, int K)
{
    __shared__ __align__(16) unsigned char lds[3][24576];

    const int tid = threadIdx.x;
    const int gx = gridDim.x;
    const int nwg = gx * gridDim.y;
    int flat = blockIdx.y * gx + blockIdx.x;
    flat = (flat & 7) * (nwg >> 3) + (flat >> 3);
    const int bm = (flat / gx) * 128;
    const int bn = (flat % gx) * 256;          // 0..1536, 256-aligned

    const int sel = bn >> 9;
    const int nloc = bn & 511;                 // 0 or 256
    const _Float16* Bg = ((sel == 0) ? QT : (sel == 1) ? KT : VT) + (size_t)nloc * K;

    const int lane = tid & 63, wv = tid >> 6;
    const int quad = lane >> 4, lrow = lane & 15;
    const int wm = (wv & 1) * 64, wn = (wv >> 1) * 128;

    f32x4 acc[4][8] = {};

    const int s2 = (lane & 7) ^ (lane >> 3);
    const int rl = 2 * (lane >> 3) + (s2 >> 2);
    const int cl = (s2 & 3) * 8;

    const _Float16* wsrc = nullptr;
    int wrb = 0, wbase = 0;
    if (wv == 0)      { wsrc = Ahg; wrb = bm;  wbase = 0; }
    else if (wv == 1) { wsrc = Bg;  wrb = 0;   wbase = 8192; }
    else if (wv == 2) { wsrc = Bg;  wrb = 128; wbase = 16384; }

    auto stage = [&](int step) {
        if (wsrc) {
            const int buf = step % 3;
            const int k0 = step << 5;
            const _Float16* s = wsrc + (size_t)(wrb + rl) * K + k0 + cl;
            #pragma unroll
            for (int ch = 0; ch < 8; ++ch)
                gl16(s + (size_t)(ch * 16) * K, &lds[buf][wbase + ch * 1024]);
        }
    };

    int offA[4], offB[8];
    #pragma unroll
    for (int mt = 0; mt < 4; ++mt) offA[mt] = swzoff(wm + mt * 16 + lrow, quad);
    #pragma unroll
    for (int nt = 0; nt < 8; ++nt) offB[nt] = 8192 + swzoff(wn + nt * 16 + lrow, quad);

    const int NT = K >> 5;
    stage(0);
    stage(1);

    for (int i = 0; i < NT; ++i) {
        if (i + 1 < NT) asm volatile("s_waitcnt vmcnt(8)" ::: "memory");
        else            asm volatile("s_waitcnt vmcnt(0)" ::: "memory");
        __builtin_amdgcn_sched_barrier(0);
        __builtin_amdgcn_s_barrier();
        __builtin_amdgcn_sched_barrier(0);

        if (i + 2 < NT) stage(i + 2);

        const unsigned char* bp = lds[i % 3];
        hfrag8 ah[4];
        #pragma unroll
        for (int mt = 0; mt < 4; ++mt)
            ah[mt] = *(const hfrag8*)(bp + offA[mt]);
        #pragma unroll
        for (int nt = 0; nt < 8; ++nt) {
            hfrag8 b = *(const hfrag8*)(bp + offB[nt]);
            #pragma unroll
            for (int mt = 0; mt < 4; ++mt)
                acc[mt][nt] = __builtin_amdgcn_mfma_f32_16x16x32_f16(ah[mt], b, acc[mt][nt], 0, 0, 0);
        }

        __builtin_amdgcn_sched_barrier(0);
        asm volatile("s_waitcnt lgkmcnt(0)" ::: "memory");
        __builtin_amdgcn_sched_barrier(0);
    }

    const int nb = M >> 9;   // batches (32)
    #pragma unroll
    for (int mt = 0; mt < 4; ++mt)
        #pragma unroll
        for (int nt = 0; nt < 8; ++nt) {
            const int ncol = nloc + wn + nt * 16 + lrow;   // 0..511 within sel
            const int head = ncol >> 6, dk = ncol & 63;
            const int m0 = bm + wm + mt * 16 + quad * 4;
            const int b_ = m0 >> 9, q = m0 & 511;
            if (sel == 2) {
                h4 v;
                #pragma unroll
                for (int reg = 0; reg < 4; ++reg) v[reg] = (_Float16)acc[mt][nt][reg];
                *(h4*)&Vo[(((size_t)head * nb + b_) * DKx + dk) * Nx + q] = v;
            } else if (sel == 1) {
                #pragma unroll
                for (int reg = 0; reg < 4; ++reg) {
                    size_t oidx = (((size_t)head * nb + b_) * Nx + (q + reg)) * DKx + dk;
                    Khg[oidx] = (_Float16)acc[mt][nt][reg];
                }
            } else {
                #pragma unroll
                for (int reg = 0; reg < 4; ++reg) {
                    hf2 s = split2h(acc[mt][nt][reg]);
                    size_t oidx = (((size_t)head * nb + b_) * Nx + (q + reg)) * DKx + dk;
                    Qhg[oidx] = s.hi;
                    Qlg[oidx] = s.lo;
                }
            }
        }
}

// ---------------------------------------------------------------------------
// MFMA flash attention: Q fp16 hi/lo planes; K single fp16; V fp16 [H,B,DK,N].
// Q frags in registers; single K/V LDS buffer + register prefetch;
// wave-parallel softmax; setprio around MFMA clusters (attn: +4-7%, m191).
// Output: heads single fp16 [TOK][D].
// ---------------------------------------------------------------------------
__global__ __launch_bounds__(256, 4) void attn_kernel(
    const _Float16* __restrict__ Qhg, const _Float16* __restrict__ Qlg,
    const _Float16* __restrict__ Khg, const _Float16* __restrict__ Vtg,
    _Float16* __restrict__ heads)
{
    __shared__ __align__(16) _Float16  Kh[64][72];
    __shared__ __align__(16) _Float16  Vt[64][72];
    __shared__ __align__(16) _Float16  Sp[64][72];
    __shared__ float ml[64], ll[64], al[64];

    const int tid = threadIdx.x;
    const int q0 = blockIdx.x * 64;
    const int hb = blockIdx.y;                 // h*Bx + b
    const size_t base = (size_t)hb * (Nx * DKx);
    const int lane = tid & 63, wv = tid >> 6;
    const int quad = lane >> 4, lrow = lane & 15;
    const int wm = (wv & 1) * 32, wn = (wv >> 1) * 32;
    const int sr = tid >> 2, sc = (tid & 3) * 16;

    // stage Q: hi through Kh, lo through Sp; pull fragments to registers
    {
        size_t off = base + (size_t)(q0 + sr) * DKx + sc;
        *(hfrag8*)&Kh[sr][sc]     = *(const hfrag8*)(Qhg + off);
        *(hfrag8*)&Kh[sr][sc + 8] = *(const hfrag8*)(Qhg + off + 8);
        *(hfrag8*)&Sp[sr][sc]     = *(const hfrag8*)(Qlg + off);
        *(hfrag8*)&Sp[sr][sc + 8] = *(const hfrag8*)(Qlg + off + 8);
    }
    if (tid < 64) { ml[tid] = -INFINITY; ll[tid] = 0.f; }
    __syncthreads();

    hfrag8 qh[2][2], qlo[2][2];
    #pragma unroll
    for (int mt = 0; mt < 2; ++mt)
        #pragma unroll
        for (int ks = 0; ks < 2; ++ks) {
            qh[mt][ks]  = *(const hfrag8*)&Kh[wm + mt * 16 + lrow][ks * 32 + quad * 8];
            qlo[mt][ks] = *(const hfrag8*)&Sp[wm + mt * 16 + lrow][ks * 32 + quad * 8];
        }
    __syncthreads();   // Q pulled; Kh/Sp free

    hfrag8 pkh[2], pv[2];
    auto loadKV = [&](int n0) {
        size_t off = base + (size_t)(n0 + sr) * DKx + sc;
        pkh[0] = *(const hfrag8*)(Khg + off);
        pkh[1] = *(const hfrag8*)(Khg + off + 8);
        const _Float16* vp = Vtg + base + (size_t)sr * Nx + n0 + sc;
        pv[0] = *(const hfrag8*)vp;
        pv[1] = *(const hfrag8*)(vp + 8);
    };
    auto storeKV = [&]() {
        *(hfrag8*)&Kh[sr][sc]     = pkh[0];
        *(hfrag8*)&Kh[sr][sc + 8] = pkh[1];
        *(hfrag8*)&Vt[sr][sc]     = pv[0];
        *(hfrag8*)&Vt[sr][sc + 8] = pv[1];
    };

    f32x4 accO[2][2] = {};

    loadKV(0); storeKV();
    __syncthreads();

    for (int n0 = 0; n0 < Nx; n0 += 64) {
        const bool more = (n0 + 64 < Nx);
        if (more) loadKV(n0 + 64);

        f32x4 accS[2][2] = {};
        __builtin_amdgcn_s_setprio(1);
        #pragma unroll
        for (int ks = 0; ks < 2; ++ks) {
            hfrag8 bh[2];
            #pragma unroll
            for (int nt = 0; nt < 2; ++nt)
                bh[nt] = *(const hfrag8*)&Kh[wn + nt * 16 + lrow][ks * 32 + quad * 8];
            #pragma unroll
            for (int mt = 0; mt < 2; ++mt)
                #pragma unroll
                for (int nt = 0; nt < 2; ++nt) {
                    accS[mt][nt] = __builtin_amdgcn_mfma_f32_16x16x32_f16(qh[mt][ks],  bh[nt], accS[mt][nt], 0, 0, 0);
                    accS[mt][nt] = __builtin_amdgcn_mfma_f32_16x16x32_f16(qlo[mt][ks], bh[nt], accS[mt][nt], 0, 0, 0);
                }
        }
        __builtin_amdgcn_s_setprio(0);
        #pragma unroll
        for (int mt = 0; mt < 2; ++mt)
            #pragma unroll
            for (int nt = 0; nt < 2; ++nt)
                #pragma unroll
                for (int reg = 0; reg < 4; ++reg)
                    Sp[wm + mt * 16 + quad * 4 + reg][wn + nt * 16 + lrow] =
                        (_Float16)(accS[mt][nt][reg] * 0.125f);
        __syncthreads();

        {
            hfrag8 s0 = *(const hfrag8*)&Sp[sr][sc];
            hfrag8 s1 = *(const hfrag8*)&Sp[sr][sc + 8];
            float rmax = -INFINITY;
            #pragma unroll
            for (int j = 0; j < 8; ++j) {
                rmax = fmaxf(rmax, (float)s0[j]);
                rmax = fmaxf(rmax, (float)s1[j]);
            }
            rmax = fmaxf(rmax, __shfl_xor(rmax, 1));
            rmax = fmaxf(rmax, __shfl_xor(rmax, 2));
            float mold = ml[sr];
            float mnew = fmaxf(mold, rmax);
            float sum = 0.f;
            hfrag8 p0, p1;
            #pragma unroll
            for (int j = 0; j < 8; ++j) {
                float pa = __expf((float)s0[j] - mnew);
                float pb = __expf((float)s1[j] - mnew);
                sum += pa + pb;
                p0[j] = (_Float16)pa;
                p1[j] = (_Float16)pb;
            }
            sum += __shfl_xor(sum, 1);
            sum += __shfl_xor(sum, 2);
            *(hfrag8*)&Sp[sr][sc]     = p0;
            *(hfrag8*)&Sp[sr][sc + 8] = p1;
            if ((tid & 3) == 0) {
                float alpha = __expf(mold - mnew);
                ml[sr] = mnew;
                ll[sr] = ll[sr] * alpha + sum;
                al[sr] = alpha;
            }
        }
        __syncthreads();

        #pragma unroll
        for (int mt = 0; mt < 2; ++mt) {
            float a0 = al[wm + mt * 16 + quad * 4 + 0];
            float a1 = al[wm + mt * 16 + quad * 4 + 1];
            float a2 = al[wm + mt * 16 + quad * 4 + 2];
            float a3 = al[wm + mt * 16 + quad * 4 + 3];
            #pragma unroll
            for (int nt = 0; nt < 2; ++nt) {
                accO[mt][nt][0] *= a0; accO[mt][nt][1] *= a1;
                accO[mt][nt][2] *= a2; accO[mt][nt][3] *= a3;
            }
        }
        __builtin_amdgcn_s_setprio(1);
        #pragma unroll
        for (int ks = 0; ks < 2; ++ks) {
            hfrag8 ap[2], bv[2];
            #pragma unroll
            for (int mt = 0; mt < 2; ++mt)
                ap[mt] = *(const hfrag8*)&Sp[wm + mt * 16 + lrow][ks * 32 + quad * 8];
            #pragma unroll
            for (int nt = 0; nt < 2; ++nt)
                bv[nt] = *(const hfrag8*)&Vt[wn + nt * 16 + lrow][ks * 32 + quad * 8];
            #pragma unroll
            for (int mt = 0; mt < 2; ++mt)
                #pragma unroll
                for (int nt = 0; nt < 2; ++nt)
                    accO[mt][nt] = __builtin_amdgcn_mfma_f32_16x16x32_f16(ap[mt], bv[nt], accO[mt][nt], 0, 0, 0);
        }
        __builtin_amdgcn_s_setprio(0);

        if (more) {
            __syncthreads();
            storeKV();
            __syncthreads();
        }
    }

    const int h_ = hb >> 5, b_ = hb & 31;
    #pragma unroll
    for (int mt = 0; mt < 2; ++mt)
        #pragma unroll
        for (int reg = 0; reg < 4; ++reg) {
            int qrow = wm + mt * 16 + quad * 4 + reg;
            float invl = 1.f / ll[qrow];
            size_t tok = (size_t)b_ * Nx + (q0 + qrow);
            #pragma unroll
            for (int nt = 0; nt < 2; ++nt) {
                int dk = wn + nt * 16 + lrow;
                heads[tok * Dx + h_ * DKx + dk] = (_Float16)(accO[mt][nt][reg] * invl);
            }
        }
}

// ---------------------------------------------------------------------------
// Reduce fused GEMM stats partials: stats[c] = sum over 256 64-row tiles.
__global__ __launch_bounds__(256) void bn_final(
    const float* __restrict__ part, float* __restrict__ stats)
{
    int c = blockIdx.x * 256 + threadIdx.x;   // 0..1023
    float s = 0.f;
    for (int rt = 0; rt < 256; ++rt) s += part[(size_t)rt * 1024 + c];
    stats[c] = s;
}

// bn_norm on packed {hi,lo} t input; optional fp32 output tee (final layer).
__global__ __launch_bounds__(256) void bn_norm(
    const h2* __restrict__ tpk, const float* __restrict__ stats,
    const void* __restrict__ g32, const void* __restrict__ g16,
    const void* __restrict__ b32, const void* __restrict__ b16,
    _Float16* __restrict__ hh, _Float16* __restrict__ hl,
    float* __restrict__ out32, const int* __restrict__ dtp)
{
    const int f32 = *dtp;
    size_t idx = (size_t)blockIdx.x * 256 + threadIdx.x;
    int c = idx & (Dx - 1);
    const float invM = 1.f / (float)TOK;
    float mu = stats[c] * invM;
    float var = stats[Dx + c] * invM - mu * mu;
    h2 tv = tpk[idx];
    float t = (float)tv[0] + (float)tv[1];
    float v = (t - mu) * rsqrtf(var + EPSx) * ldsel(g32, g16, c, f32) + ldsel(b32, b16, c, f32);
    hf2 s = split2h(v);
    hh[idx] = s.hi; hl[idx] = s.lo;
    if (out32) out32[idx] = v;
}

// ---------------------------------------------------------------------------
__global__ __launch_bounds__(256) void out_mean_part(
    const _Float16* __restrict__ hh, const _Float16* __restrict__ hl, float* __restrict__ part)
{
    int b = blockIdx.x;        // 32
    int g = blockIdx.y;        // 8 groups of 64 rows
    int d = threadIdx.x;       // 256; covers 512 d in 2 strides
    float s0 = 0.f, s1 = 0.f;
    for (int n = g * 64; n < g * 64 + 64; ++n) {
        size_t idx = ((size_t)b * Nx + n) * Dx;
        s0 += (float)hh[idx + d]       + (float)hl[idx + d];
        s1 += (float)hh[idx + d + 256] + (float)hl[idx + d + 256];
    }
    part[((size_t)b * 8 + g) * Dx + d]       = s0;
    part[((size_t)b * 8 + g) * Dx + d + 256] = s1;
}

__global__ __launch_bounds__(256) void out_mean_final(
    const float* __restrict__ part, float* __restrict__ out2)
{
    size_t o = (size_t)blockIdx.x * 256 + threadIdx.x;   // b*512 + d
    int b = (int)(o >> 9), d = (int)(o & 511);
    float s = 0.f;
    #pragma unroll
    for (int g = 0; g < 8; ++g) s += part[((size_t)b * 8 + g) * Dx + d];
    out2[o] = s * (1.f / (float)Nx);
}

// ---------------------------------------------------------------------------
extern "C" void kernel_launch(void* const* d_in, const int* in_sizes, int n_in,
                              void* d_out, int out_size, void* d_ws, size_t ws_size,
                              hipStream_t stream)
{
    const void* x   = d_in[0];
    const void* We  = d_in[1];
    const void* be  = d_in[2];
    const void* Wq  = d_in[3];
    const void* Wk  = d_in[4];
    const void* Wv  = d_in[5];
    const void* Wo  = d_in[6];
    const void* g1  = d_in[7];
    const void* b1  = d_in[8];
    const void* W1  = d_in[9];
    const void* bb1 = d_in[10];
    const void* W2  = d_in[11];
    const void* bb2 = d_in[12];
    const void* g2  = d_in[13];
    const void* b2  = d_in[14];

    const size_t szHD = (size_t)TOK * Dx;            // 8,388,608
    const size_t QKN  = (size_t)Hx * Bx * Nx * DKx;  // 8,388,608
    const size_t szQT = (size_t)3 * Hx * DKx * Dx;   // per q/k/v array, all layers
    const size_t szW1 = (size_t)3 * FFx * Dx;
    const size_t szWqkvL = (size_t)Hx * Dx * DKx;    // per-layer stride 262,144

    // workspace layout:
    // tpk (packed h2) | stats | dtp | hh,hl fp16 | region | weights | part
    h2* tpk        = (h2*)d_ws;
    float* stats   = (float*)(tpk + szHD);
    int*   dtp     = (int*)(stats + 2 * Dx);
    _Float16* hh   = (_Float16*)(stats + 2 * Dx + 64);
    _Float16* hl   = hh + szHD;
    _Float16* region = hl + szHD;

    // attn-phase views inside region
    _Float16* heads = region;
    _Float16* Qhg   = heads + szHD;
    _Float16* Qlg   = Qhg + QKN;
    _Float16* Khg   = Qlg + QKN;
    _Float16* Vtg   = Khg + QKN;
    // FF-phase view: ffbuf fp16 [TOK, FFx] (67MB), overlaps heads..Vtg (80MB)
    _Float16* ffbuf = region;

    // weight planes (persistent, all layers, single fp16)
    _Float16* WqT = Vtg + QKN;
    _Float16* WkT = WqT + szQT;
    _Float16* WvT = WkT + szQT;
    _Float16* WoT = WvT + szQT;
    _Float16* W1c = WoT + szQT;
    _Float16* W2c = W1c + szW1;
    float*    part = (float*)(W2c + szW1);           // 256*1024 fp32 = 1 MB

    auto p32 = [](const void* p, size_t e) { return (const void*)((const float*)p + e); };
    auto p16 = [](const void* p, size_t e) { return (const void*)((const __hip_bfloat16*)p + e); };

    detect_kernel<<<1, 64, 0, stream>>>(x, dtp);

    // one-time weight conversion (fp16 single-plane, pre-transposed where needed)
    transpose_cvt_kernel<<<dim3(1, 8, 24), 256, 0, stream>>>(Wq, WqT, Dx, DKx, dtp);
    transpose_cvt_kernel<<<dim3(1, 8, 24), 256, 0, stream>>>(Wk, WkT, Dx, DKx, dtp);
    transpose_cvt_kernel<<<dim3(1, 8, 24), 256, 0, stream>>>(Wv, WvT, Dx, DKx, dtp);
    transpose_cvt_kernel<<<dim3(8, 8, 3), 256, 0, stream>>>(Wo, WoT, Dx, Dx, dtp);
    cvt_kernel<<<szW1 / 256, 256, 0, stream>>>(W1, W1c, dtp);
    cvt_kernel<<<szW1 / 256, 256, 0, stream>>>(W2, W2c, dtp);

    embed_kernel<<<TOK * Dx / 256, 256, 0, stream>>>(x, We, be, hh, hl, dtp);

    const dim3 gQKV(6, TOK / 128);                    // 768 blocks (BN=256)
    const dim3 gWo(Dx / 256, TOK / 128);              // 256 blocks
    const dim3 gAttn(Nx / 64, Hx * Bx);               // 2048 blocks
    const dim3 gFF1(FFx / 256, TOK / 128);            // 1024 blocks
    const dim3 gFF2(Dx / 256, TOK / 128);             // 256 blocks
    const size_t partBytes = 256 * 1024 * sizeof(float);
    for (int l = 0; l < 3; ++l) {
        const size_t eQ = (size_t)l * szWqkvL;
        const size_t e1 = (size_t)l * FFx * Dx;
        const size_t eD = (size_t)l * Dx, eF = (size_t)l * FFx;
        const bool last = (l == 2);

        qkv_mfma<<<gQKV, 256, 0, stream>>>(
            hh, WqT + eQ, WkT + eQ, WvT + eQ,
            Qhg, Qlg, Khg, Vtg, TOK, Dx);
        attn_kernel<<<gAttn, 256, 0, stream>>>(Qhg, Qlg, Khg, Vtg, heads);

        // output projection + residual -> packed t ; fused stats
        hipMemsetAsync(part, 0, partBytes, stream);
        gemm3<2, 2, 1><<<gWo, 256, 0, stream>>>(
            heads, WoT + eQ,
            nullptr, nullptr, hh, hl, tpk, part, TOK, Dx, Dx, dtp);
        bn_final<<<4, 256, 0, stream>>>(part, stats);
        bn_norm<<<TOK * Dx / 256, 256, 0, stream>>>(
            tpk, stats, p32(g1, eD), p16(g1, eD), p32(b1, eD), p16(b1, eD),
            hh, hl, nullptr, dtp);

        // FF
        gemm3<1, 1, 0><<<gFF1, 256, 0, stream>>>(
            hh, W1c + e1,
            p32(bb1, eF), p16(bb1, eF), nullptr, nullptr, ffbuf, nullptr,
            TOK, FFx, Dx, dtp);
        hipMemsetAsync(part, 0, partBytes, stream);
        gemm3<2, 2, 1><<<gFF2, 256, 0, stream>>>(
            ffbuf, W2c + e1,
            p32(bb2, eD), p16(bb2, eD), hh, hl, tpk, part, TOK, Dx, FFx, dtp);
        bn_final<<<4, 256, 0, stream>>>(part, stats);
        bn_norm<<<TOK * Dx / 256, 256, 0, stream>>>(
            tpk, stats, p32(g2, eD), p16(g2, eD), p32(b2, eD), p16(b2, eD),
            hh, hl, last ? (float*)d_out : nullptr, dtp);
    }

    out_mean_part<<<dim3(Bx, 8), 256, 0, stream>>>(hh, hl, part);
    out_mean_final<<<Bx * Dx / 256, 256, 0, stream>>>(part, (float*)d_out + (size_t)TOK * Dx);
}

// Round 14
// 1164.052 us; speedup vs baseline: 1.0892x; 1.0892x over previous
//
#include <hip/hip_runtime.h>
#include <hip/hip_bf16.h>

// Problem constants
#define Bx 32
#define Nx 512
#define Dx 512
#define Hx 8
#define DKx 64
#define FFx 2048
#define TOK (Bx * Nx)          // 16384 tokens
#define EPSx 1e-5f

typedef float  f32x4  __attribute__((ext_vector_type(4)));
typedef _Float16 hfrag8 __attribute__((ext_vector_type(8)));
typedef _Float16 h4     __attribute__((ext_vector_type(4)));
typedef _Float16 h2     __attribute__((ext_vector_type(2)));

struct hf2 { _Float16 hi, lo; };
__device__ __forceinline__ hf2 split2h(float v) {
    _Float16 h = (_Float16)v;
    hf2 r; r.hi = h; r.lo = (_Float16)(v - (float)h);
    return r;
}

// Direct global->LDS DMA, 16B per lane. LDS dest = wave-uniform base + lane*16.
__device__ __forceinline__ void gl16(const void* g, void* l) {
    __builtin_amdgcn_global_load_lds(
        (const __attribute__((address_space(1))) unsigned int*)g,
        (__attribute__((address_space(3))) unsigned int*)l, 16, 0, 0);
}

// Swizzled byte offset within an 8KB plane for logical (row, 16B-slot q).
// Physical row = row>>1 (128B, bank-neutral); slot = (((row&1)<<2)|q) ^ (prow&7).
__device__ __forceinline__ int swzoff(int row, int q) {
    int p = row >> 1;
    int sl = ((row & 1) << 2) | q;
    int s = sl ^ (p & 7);
    return p * 128 + s * 16;
}

// ---------------------------------------------------------------------------
__device__ __forceinline__ float ldsel(const void* p32, const void* p16, size_t i, int f32) {
    return f32 ? ((const float*)p32)[i]
               : __bfloat162float(((const __hip_bfloat16*)p16)[i]);
}

__global__ void detect_kernel(const void* __restrict__ x, int* __restrict__ flag)
{
    if (threadIdx.x == 0 && blockIdx.x == 0) {
        const unsigned short* u = (const unsigned short*)x;
        int hits = 0;
        for (int i = 0; i < 256; ++i) {
            int e = (u[i] >> 7) & 0xFF;
            if (e >= 0x86) ++hits;
        }
        *flag = (hits > 8) ? 1 : 0;
    }
}

// ---------------------------------------------------------------------------
// Weight conversion: elementwise cast to single fp16 plane.
__global__ __launch_bounds__(256) void cvt_kernel(
    const void* __restrict__ W, _Float16* __restrict__ o, const int* __restrict__ dtp)
{
    const int f32 = *dtp;
    size_t idx = (size_t)blockIdx.x * 256 + threadIdx.x;
    o[idx] = (_Float16)ldsel(W, W, idx, f32);
}

// Weight conversion: transpose [R][C] -> [C][R] per matrix (blockIdx.z), fp16.
__global__ __launch_bounds__(256) void transpose_cvt_kernel(
    const void* __restrict__ W, _Float16* __restrict__ o,
    int R, int C, const int* __restrict__ dtp)
{
    const int f32 = *dtp;
    __shared__ float tile[64][65];
    const size_t mbase = (size_t)blockIdx.z * R * C;
    const int c0 = blockIdx.x * 64, r0 = blockIdx.y * 64;
    const int tc = threadIdx.x & 63, tg = threadIdx.x >> 6;
    #pragma unroll
    for (int i = 0; i < 16; ++i) {
        int r = tg * 16 + i;
        tile[r][tc] = ldsel(W, W, mbase + (size_t)(r0 + r) * C + c0 + tc, f32);
    }
    __syncthreads();
    #pragma unroll
    for (int i = 0; i < 16; ++i) {
        int cc = tg * 16 + i;
        o[mbase + (size_t)(c0 + cc) * R + r0 + tc] = (_Float16)tile[tc][cc];
    }
}

// ---------------------------------------------------------------------------
__global__ __launch_bounds__(256) void embed_kernel(
    const void* __restrict__ x, const void* __restrict__ We,
    const void* __restrict__ be, _Float16* __restrict__ hh, _Float16* __restrict__ hl,
    const int* __restrict__ dtp)
{
    const int f32 = *dtp;
    size_t idx = (size_t)blockIdx.x * 256 + threadIdx.x;
    int d = idx & (Dx - 1);
    size_t t = idx >> 9;
    float v = ldsel(x, x, t * 2, f32)     * ldsel(We, We, d * 2, f32) +
              ldsel(x, x, t * 2 + 1, f32) * ldsel(We, We, d * 2 + 1, f32) +
              ldsel(be, be, d, f32);
    hf2 s = split2h(v);
    hh[idx] = s.hi; hl[idx] = s.lo;
}

// ---------------------------------------------------------------------------
// MFMA GEMM, single-fp16 A and B planes. 128x128 tile, BK=32, 2x2 wave grid.
// ROUND-9 PROVEN OPTIMUM: 3-buffer LDS pipeline fed by global_load_lds,
// ONE barrier per K-step:
//   iter i: vmcnt(8) gate (stage-i landed) ; s_barrier ; stage step i+2 ;
//           ds_read buf(i%3)+MFMA ; lgkmcnt(0)
// Waves 0,1 stage (8 chunks each); waves 2,3 load-free (role-split — the
// free gate-pass keeps the MFMA pipe warm; all-wave staging measured -37us).
// 48 KB LDS -> 3 blk/CU. XOR-swizzled planes, 0 bank conflicts.
// Elimination table (r10-13): depth, occupancy, barrier count, tile shape
// all non-binding; the structure sits at ~10-13 B/cyc/CU staging throughput.
// STATS: fused per-column sum/sumsq partials (N==512), 128-row tile units.
// EPI: 1 +bias,relu ; 2 +bias(opt)+resid(fp16 planes).
// OHF: 0 fp32 out ; 1 fp16 single ; 2 packed {hi,lo} h2 out.
// ---------------------------------------------------------------------------
template <int EPI, int OHF, int STATS>
__global__ __launch_bounds__(256, 3) void gemm3(
    const _Float16* __restrict__ Ahg, const _Float16* __restrict__ Bg,
    const void* __restrict__ bias32, const void* __restrict__ bias16,
    const _Float16* __restrict__ residH, const _Float16* __restrict__ residL,
    void* __restrict__ outp, float* __restrict__ part,
    int M, int N, int K, const int* __restrict__ dtp)
{
    const int f32 = *dtp;
    __shared__ __align__(16) unsigned char lds[3][2 * 8192];

    const int tid = threadIdx.x;
    // XCD-aware bijective swizzle (nwg % 8 == 0).
    const int gx = gridDim.x;
    const int nwg = gx * gridDim.y;
    int flat = blockIdx.y * gx + blockIdx.x;
    flat = (flat & 7) * (nwg >> 3) + (flat >> 3);
    const int bm = (flat / gx) * 128;
    const int bn = (flat % gx) * 128;

    const int lane = tid & 63, wv = tid >> 6;
    const int quad = lane >> 4, lrow = lane & 15;
    const int wm = (wv & 1) * 64, wn = (wv >> 1) * 64;

    f32x4 acc[4][4] = {};

    // staging lane-constants (inverse of the read swizzle)
    const int s2 = (lane & 7) ^ (lane >> 3);
    const int rl = 2 * (lane >> 3) + (s2 >> 2);   // row within 16-row chunk
    const int cl = (s2 & 3) * 8;                  // k element offset

    const bool doStage = (wv < 2);
    const _Float16* wsrc = (wv == 0) ? Ahg : Bg;
    const int wrb = (wv == 0) ? bm : bn;

    auto stage = [&](int step) {
        if (doStage) {
            const int buf = step % 3;
            const int k0 = step << 5;
            const _Float16* s = wsrc + (size_t)(wrb + rl) * K + k0 + cl;
            #pragma unroll
            for (int ch = 0; ch < 8; ++ch)
                gl16(s + (size_t)(ch * 16) * K, &lds[buf][wv * 8192 + ch * 1024]);
        }
    };

    // precomputed fragment byte offsets (buffer-relative)
    int offA[4], offB[4];
    #pragma unroll
    for (int mt = 0; mt < 4; ++mt) offA[mt] = swzoff(wm + mt * 16 + lrow, quad);
    #pragma unroll
    for (int nt = 0; nt < 4; ++nt) offB[nt] = 8192 + swzoff(wn + nt * 16 + lrow, quad);

    const int NT = K >> 5;
    stage(0);
    stage(1);

    for (int i = 0; i < NT; ++i) {
        // wait for my stage-for-step-i only; stage(i+1) stays in flight
        if (i + 1 < NT) asm volatile("s_waitcnt vmcnt(8)" ::: "memory");
        else            asm volatile("s_waitcnt vmcnt(0)" ::: "memory");
        __builtin_amdgcn_sched_barrier(0);
        __builtin_amdgcn_s_barrier();   // step-i data resident; buf (i+2)%3 free
        __builtin_amdgcn_sched_barrier(0);

        if (i + 2 < NT) stage(i + 2);

        const unsigned char* bp = lds[i % 3];
        hfrag8 ah[4];
        #pragma unroll
        for (int mt = 0; mt < 4; ++mt)
            ah[mt] = *(const hfrag8*)(bp + offA[mt]);
        #pragma unroll
        for (int nt = 0; nt < 4; ++nt) {
            hfrag8 b = *(const hfrag8*)(bp + offB[nt]);
            #pragma unroll
            for (int mt = 0; mt < 4; ++mt)
                acc[mt][nt] = __builtin_amdgcn_mfma_f32_16x16x32_f16(ah[mt], b, acc[mt][nt], 0, 0, 0);
        }

        __builtin_amdgcn_sched_barrier(0);
        asm volatile("s_waitcnt lgkmcnt(0)" ::: "memory");   // my reads of buf i done
        __builtin_amdgcn_sched_barrier(0);
    }

    #pragma unroll
    for (int nt = 0; nt < 4; ++nt) {
        const int n = bn + wn + nt * 16 + lrow;
        float cs = 0.f, cq = 0.f;
        #pragma unroll
        for (int mt = 0; mt < 4; ++mt)
            #pragma unroll
            for (int reg = 0; reg < 4; ++reg) {
                int m = bm + wm + mt * 16 + quad * 4 + reg;
                float v = acc[mt][nt][reg];
                if constexpr (EPI == 1) { v += ldsel(bias32, bias16, n, f32); v = fmaxf(v, 0.f); }
                if constexpr (EPI == 2) {
                    if (bias32) v += ldsel(bias32, bias16, n, f32);
                    size_t ridx = (size_t)m * N + n;
                    v += (float)residH[ridx] + (float)residL[ridx];
                }
                size_t oidx = (size_t)m * N + n;
                if constexpr (OHF == 1) ((_Float16*)outp)[oidx] = (_Float16)v;
                else if constexpr (OHF == 2) {
                    hf2 s = split2h(v);
                    h2 pk; pk[0] = s.hi; pk[1] = s.lo;
                    ((h2*)outp)[oidx] = pk;           // single 4B store stream
                }
                else ((float*)outp)[oidx] = v;
                if constexpr (STATS) { cs += v; cq += v * v; }
            }
        if constexpr (STATS) {
            cs += __shfl_xor(cs, 16); cs += __shfl_xor(cs, 32);
            cq += __shfl_xor(cq, 16); cq += __shfl_xor(cq, 32);
            if (quad == 0) {
                float* pb = part + (size_t)(bm >> 7) * 1024;
                atomicAdd(&pb[n], cs);          // 2 waves share a column
                atomicAdd(&pb[512 + n], cq);
            }
        }
    }
}

// ---------------------------------------------------------------------------
// Fused QKV projection: round-9 pipeline. grid.x=12.
// Q,K out single fp16 [H,B,N,DK]; V fp16 transposed [H,B,DK,N].
// ---------------------------------------------------------------------------
__global__ __launch_bounds__(256, 3) void qkv_mfma(
    const _Float16* __restrict__ Ahg,
    const _Float16* __restrict__ QT, const _Float16* __restrict__ KT,
    const _Float16* __restrict__ VT,
    _Float16* __restrict__ Qhg, _Float16* __restrict__ Khg,
    _Float16* __restrict__ Vo, int M, int K)
{
    __shared__ __align__(16) unsigned char lds[3][2 * 8192];

    const int tid = threadIdx.x;
    const int gx = gridDim.x;
    const int nwg = gx * gridDim.y;
    int flat = blockIdx.y * gx + blockIdx.x;
    flat = (flat & 7) * (nwg >> 3) + (flat >> 3);
    const int bm = (flat / gx) * 128;
    const int bn = (flat % gx) * 128;          // 0..1536, 128-aligned

    const int sel = bn >> 9;
    const int nloc = bn & 511;
    const _Float16* Bg = ((sel == 0) ? QT : (sel == 1) ? KT : VT) + (size_t)nloc * K;

    const int lane = tid & 63, wv = tid >> 6;
    const int quad = lane >> 4, lrow = lane & 15;
    const int wm = (wv & 1) * 64, wn = (wv >> 1) * 64;

    f32x4 acc[4][4] = {};

    const int s2 = (lane & 7) ^ (lane >> 3);
    const int rl = 2 * (lane >> 3) + (s2 >> 2);
    const int cl = (s2 & 3) * 8;

    const bool doStage = (wv < 2);
    const _Float16* wsrc = (wv == 0) ? Ahg : Bg;
    const int wrb = (wv == 0) ? bm : 0;

    auto stage = [&](int step) {
        if (doStage) {
            const int buf = step % 3;
            const int k0 = step << 5;
            const _Float16* s = wsrc + (size_t)(wrb + rl) * K + k0 + cl;
            #pragma unroll
            for (int ch = 0; ch < 8; ++ch)
                gl16(s + (size_t)(ch * 16) * K, &lds[buf][wv * 8192 + ch * 1024]);
        }
    };

    int offA[4], offB[4];
    #pragma unroll
    for (int mt = 0; mt < 4; ++mt) offA[mt] = swzoff(wm + mt * 16 + lrow, quad);
    #pragma unroll
    for (int nt = 0; nt < 4; ++nt) offB[nt] = 8192 + swzoff(wn + nt * 16 + lrow, quad);

    const int NT = K >> 5;
    stage(0);
    stage(1);

    for (int i = 0; i < NT; ++i) {
        if (i + 1 < NT) asm volatile("s_waitcnt vmcnt(8)" ::: "memory");
        else            asm volatile("s_waitcnt vmcnt(0)" ::: "memory");
        __builtin_amdgcn_sched_barrier(0);
        __builtin_amdgcn_s_barrier();
        __builtin_amdgcn_sched_barrier(0);

        if (i + 2 < NT) stage(i + 2);

        const unsigned char* bp = lds[i % 3];
        hfrag8 ah[4];
        #pragma unroll
        for (int mt = 0; mt < 4; ++mt)
            ah[mt] = *(const hfrag8*)(bp + offA[mt]);
        #pragma unroll
        for (int nt = 0; nt < 4; ++nt) {
            hfrag8 b = *(const hfrag8*)(bp + offB[nt]);
            #pragma unroll
            for (int mt = 0; mt < 4; ++mt)
                acc[mt][nt] = __builtin_amdgcn_mfma_f32_16x16x32_f16(ah[mt], b, acc[mt][nt], 0, 0, 0);
        }

        __builtin_amdgcn_sched_barrier(0);
        asm volatile("s_waitcnt lgkmcnt(0)" ::: "memory");
        __builtin_amdgcn_sched_barrier(0);
    }

    const int nb = M >> 9;   // batches (32)
    #pragma unroll
    for (int mt = 0; mt < 4; ++mt)
        #pragma unroll
        for (int nt = 0; nt < 4; ++nt) {
            const int ncol = nloc + wn + nt * 16 + lrow;   // 0..511 within sel
            const int head = ncol >> 6, dk = ncol & 63;
            const int m0 = bm + wm + mt * 16 + quad * 4;
            const int b_ = m0 >> 9, q = m0 & 511;
            if (sel == 2) {
                h4 v;
                #pragma unroll
                for (int reg = 0; reg < 4; ++reg) v[reg] = (_Float16)acc[mt][nt][reg];
                *(h4*)&Vo[(((size_t)head * nb + b_) * DKx + dk) * Nx + q] = v;
            } else {
                _Float16* op = (sel == 1) ? Khg : Qhg;
                #pragma unroll
                for (int reg = 0; reg < 4; ++reg) {
                    size_t oidx = (((size_t)head * nb + b_) * Nx + (q + reg)) * DKx + dk;
                    op[oidx] = (_Float16)acc[mt][nt][reg];
                }
            }
        }
}

// ---------------------------------------------------------------------------
// MFMA flash attention: Q,K single fp16 [H,B,N,DK]; V fp16 [H,B,DK,N].
// Q frags in registers (single plane — QK^T is 1 MFMA per fragment pair);
// single K/V LDS buffer + register prefetch; wave-parallel softmax;
// setprio around MFMA clusters. Output: heads single fp16 [TOK][D].
// ---------------------------------------------------------------------------
__global__ __launch_bounds__(256, 4) void attn_kernel(
    const _Float16* __restrict__ Qhg, const _Float16* __restrict__ Khg,
    const _Float16* __restrict__ Vtg, _Float16* __restrict__ heads)
{
    __shared__ __align__(16) _Float16  Kh[64][72];
    __shared__ __align__(16) _Float16  Vt[64][72];
    __shared__ __align__(16) _Float16  Sp[64][72];
    __shared__ float ml[64], ll[64], al[64];

    const int tid = threadIdx.x;
    const int q0 = blockIdx.x * 64;
    const int hb = blockIdx.y;                 // h*Bx + b
    const size_t base = (size_t)hb * (Nx * DKx);
    const int lane = tid & 63, wv = tid >> 6;
    const int quad = lane >> 4, lrow = lane & 15;
    const int wm = (wv & 1) * 32, wn = (wv >> 1) * 32;
    const int sr = tid >> 2, sc = (tid & 3) * 16;

    // stage Q through Kh once; pull fragments to registers
    {
        size_t off = base + (size_t)(q0 + sr) * DKx + sc;
        *(hfrag8*)&Kh[sr][sc]     = *(const hfrag8*)(Qhg + off);
        *(hfrag8*)&Kh[sr][sc + 8] = *(const hfrag8*)(Qhg + off + 8);
    }
    if (tid < 64) { ml[tid] = -INFINITY; ll[tid] = 0.f; }
    __syncthreads();

    hfrag8 qh[2][2];
    #pragma unroll
    for (int mt = 0; mt < 2; ++mt)
        #pragma unroll
        for (int ks = 0; ks < 2; ++ks)
            qh[mt][ks] = *(const hfrag8*)&Kh[wm + mt * 16 + lrow][ks * 32 + quad * 8];
    __syncthreads();   // Q pulled; Kh free

    hfrag8 pkh[2], pv[2];
    auto loadKV = [&](int n0) {
        size_t off = base + (size_t)(n0 + sr) * DKx + sc;
        pkh[0] = *(const hfrag8*)(Khg + off);
        pkh[1] = *(const hfrag8*)(Khg + off + 8);
        const _Float16* vp = Vtg + base + (size_t)sr * Nx + n0 + sc;
        pv[0] = *(const hfrag8*)vp;
        pv[1] = *(const hfrag8*)(vp + 8);
    };
    auto storeKV = [&]() {
        *(hfrag8*)&Kh[sr][sc]     = pkh[0];
        *(hfrag8*)&Kh[sr][sc + 8] = pkh[1];
        *(hfrag8*)&Vt[sr][sc]     = pv[0];
        *(hfrag8*)&Vt[sr][sc + 8] = pv[1];
    };

    f32x4 accO[2][2] = {};

    loadKV(0); storeKV();
    __syncthreads();

    for (int n0 = 0; n0 < Nx; n0 += 64) {
        const bool more = (n0 + 64 < Nx);
        if (more) loadKV(n0 + 64);

        f32x4 accS[2][2] = {};
        __builtin_amdgcn_s_setprio(1);
        #pragma unroll
        for (int ks = 0; ks < 2; ++ks) {
            hfrag8 bh[2];
            #pragma unroll
            for (int nt = 0; nt < 2; ++nt)
                bh[nt] = *(const hfrag8*)&Kh[wn + nt * 16 + lrow][ks * 32 + quad * 8];
            #pragma unroll
            for (int mt = 0; mt < 2; ++mt)
                #pragma unroll
                for (int nt = 0; nt < 2; ++nt)
                    accS[mt][nt] = __builtin_amdgcn_mfma_f32_16x16x32_f16(qh[mt][ks], bh[nt], accS[mt][nt], 0, 0, 0);
        }
        __builtin_amdgcn_s_setprio(0);
        #pragma unroll
        for (int mt = 0; mt < 2; ++mt)
            #pragma unroll
            for (int nt = 0; nt < 2; ++nt)
                #pragma unroll
                for (int reg = 0; reg < 4; ++reg)
                    Sp[wm + mt * 16 + quad * 4 + reg][wn + nt * 16 + lrow] =
                        (_Float16)(accS[mt][nt][reg] * 0.125f);
        __syncthreads();

        {
            hfrag8 s0 = *(const hfrag8*)&Sp[sr][sc];
            hfrag8 s1 = *(const hfrag8*)&Sp[sr][sc + 8];
            float rmax = -INFINITY;
            #pragma unroll
            for (int j = 0; j < 8; ++j) {
                rmax = fmaxf(rmax, (float)s0[j]);
                rmax = fmaxf(rmax, (float)s1[j]);
            }
            rmax = fmaxf(rmax, __shfl_xor(rmax, 1));
            rmax = fmaxf(rmax, __shfl_xor(rmax, 2));
            float mold = ml[sr];
            float mnew = fmaxf(mold, rmax);
            float sum = 0.f;
            hfrag8 p0, p1;
            #pragma unroll
            for (int j = 0; j < 8; ++j) {
                float pa = __expf((float)s0[j] - mnew);
                float pb = __expf((float)s1[j] - mnew);
                sum += pa + pb;
                p0[j] = (_Float16)pa;
                p1[j] = (_Float16)pb;
            }
            sum += __shfl_xor(sum, 1);
            sum += __shfl_xor(sum, 2);
            *(hfrag8*)&Sp[sr][sc]     = p0;
            *(hfrag8*)&Sp[sr][sc + 8] = p1;
            if ((tid & 3) == 0) {
                float alpha = __expf(mold - mnew);
                ml[sr] = mnew;
                ll[sr] = ll[sr] * alpha + sum;
                al[sr] = alpha;
            }
        }
        __syncthreads();

        #pragma unroll
        for (int mt = 0; mt < 2; ++mt) {
            float a0 = al[wm + mt * 16 + quad * 4 + 0];
            float a1 = al[wm + mt * 16 + quad * 4 + 1];
            float a2 = al[wm + mt * 16 + quad * 4 + 2];
            float a3 = al[wm + mt * 16 + quad * 4 + 3];
            #pragma unroll
            for (int nt = 0; nt < 2; ++nt) {
                accO[mt][nt][0] *= a0; accO[mt][nt][1] *= a1;
                accO[mt][nt][2] *= a2; accO[mt][nt][3] *= a3;
            }
        }
        __builtin_amdgcn_s_setprio(1);
        #pragma unroll
        for (int ks = 0; ks < 2; ++ks) {
            hfrag8 ap[2], bv[2];
            #pragma unroll
            for (int mt = 0; mt < 2; ++mt)
                ap[mt] = *(const hfrag8*)&Sp[wm + mt * 16 + lrow][ks * 32 + quad * 8];
            #pragma unroll
            for (int nt = 0; nt < 2; ++nt)
                bv[nt] = *(const hfrag8*)&Vt[wn + nt * 16 + lrow][ks * 32 + quad * 8];
            #pragma unroll
            for (int mt = 0; mt < 2; ++mt)
                #pragma unroll
                for (int nt = 0; nt < 2; ++nt)
                    accO[mt][nt] = __builtin_amdgcn_mfma_f32_16x16x32_f16(ap[mt], bv[nt], accO[mt][nt], 0, 0, 0);
        }
        __builtin_amdgcn_s_setprio(0);

        if (more) {
            __syncthreads();
            storeKV();
            __syncthreads();
        }
    }

    const int h_ = hb >> 5, b_ = hb & 31;
    #pragma unroll
    for (int mt = 0; mt < 2; ++mt)
        #pragma unroll
        for (int reg = 0; reg < 4; ++reg) {
            int qrow = wm + mt * 16 + quad * 4 + reg;
            float invl = 1.f / ll[qrow];
            size_t tok = (size_t)b_ * Nx + (q0 + qrow);
            #pragma unroll
            for (int nt = 0; nt < 2; ++nt) {
                int dk = wn + nt * 16 + lrow;
                heads[tok * Dx + h_ * DKx + dk] = (_Float16)(accO[mt][nt][reg] * invl);
            }
        }
}

// ---------------------------------------------------------------------------
// Reduce fused GEMM stats partials: stats[c] = sum over 128 row-tiles.
__global__ __launch_bounds__(256) void bn_final(
    const float* __restrict__ part, float* __restrict__ stats)
{
    int c = blockIdx.x * 256 + threadIdx.x;   // 0..1023
    float s = 0.f;
    for (int rt = 0; rt < 128; ++rt) s += part[(size_t)rt * 1024 + c];
    stats[c] = s;
}

// bn_norm on packed {hi,lo} t input; optional fp32 output tee (final layer).
__global__ __launch_bounds__(256) void bn_norm(
    const h2* __restrict__ tpk, const float* __restrict__ stats,
    const void* __restrict__ g32, const void* __restrict__ g16,
    const void* __restrict__ b32, const void* __restrict__ b16,
    _Float16* __restrict__ hh, _Float16* __restrict__ hl,
    float* __restrict__ out32, const int* __restrict__ dtp)
{
    const int f32 = *dtp;
    size_t idx = (size_t)blockIdx.x * 256 + threadIdx.x;
    int c = idx & (Dx - 1);
    const float invM = 1.f / (float)TOK;
    float mu = stats[c] * invM;
    float var = stats[Dx + c] * invM - mu * mu;
    h2 tv = tpk[idx];
    float t = (float)tv[0] + (float)tv[1];
    float v = (t - mu) * rsqrtf(var + EPSx) * ldsel(g32, g16, c, f32) + ldsel(b32, b16, c, f32);
    hf2 s = split2h(v);
    hh[idx] = s.hi; hl[idx] = s.lo;
    if (out32) out32[idx] = v;
}

// ---------------------------------------------------------------------------
__global__ __launch_bounds__(256) void out_mean_part(
    const _Float16* __restrict__ hh, const _Float16* __restrict__ hl, float* __restrict__ part)
{
    int b = blockIdx.x;        // 32
    int g = blockIdx.y;        // 8 groups of 64 rows
    int d = threadIdx.x;       // 256; covers 512 d in 2 strides
    float s0 = 0.f, s1 = 0.f;
    for (int n = g * 64; n < g * 64 + 64; ++n) {
        size_t idx = ((size_t)b * Nx + n) * Dx;
        s0 += (float)hh[idx + d]       + (float)hl[idx + d];
        s1 += (float)hh[idx + d + 256] + (float)hl[idx + d + 256];
    }
    part[((size_t)b * 8 + g) * Dx + d]       = s0;
    part[((size_t)b * 8 + g) * Dx + d + 256] = s1;
}

__global__ __launch_bounds__(256) void out_mean_final(
    const float* __restrict__ part, float* __restrict__ out2)
{
    size_t o = (size_t)blockIdx.x * 256 + threadIdx.x;   // b*512 + d
    int b = (int)(o >> 9), d = (int)(o & 511);
    float s = 0.f;
    #pragma unroll
    for (int g = 0; g < 8; ++g) s += part[((size_t)b * 8 + g) * Dx + d];
    out2[o] = s * (1.f / (float)Nx);
}

// ---------------------------------------------------------------------------
extern "C" void kernel_launch(void* const* d_in, const int* in_sizes, int n_in,
                              void* d_out, int out_size, void* d_ws, size_t ws_size,
                              hipStream_t stream)
{
    const void* x   = d_in[0];
    const void* We  = d_in[1];
    const void* be  = d_in[2];
    const void* Wq  = d_in[3];
    const void* Wk  = d_in[4];
    const void* Wv  = d_in[5];
    const void* Wo  = d_in[6];
    const void* g1  = d_in[7];
    const void* b1  = d_in[8];
    const void* W1  = d_in[9];
    const void* bb1 = d_in[10];
    const void* W2  = d_in[11];
    const void* bb2 = d_in[12];
    const void* g2  = d_in[13];
    const void* b2  = d_in[14];

    const size_t szHD = (size_t)TOK * Dx;            // 8,388,608
    const size_t QKN  = (size_t)Hx * Bx * Nx * DKx;  // 8,388,608
    const size_t szQT = (size_t)3 * Hx * DKx * Dx;   // per q/k/v array, all layers
    const size_t szW1 = (size_t)3 * FFx * Dx;
    const size_t szWqkvL = (size_t)Hx * Dx * DKx;    // per-layer stride 262,144

    // workspace layout:
    // tpk (packed h2) | stats | dtp | hh,hl fp16 | region | weights | part
    h2* tpk        = (h2*)d_ws;
    float* stats   = (float*)(tpk + szHD);
    int*   dtp     = (int*)(stats + 2 * Dx);
    _Float16* hh   = (_Float16*)(stats + 2 * Dx + 64);
    _Float16* hl   = hh + szHD;
    _Float16* region = hl + szHD;

    // attn-phase views inside region
    _Float16* heads = region;
    _Float16* Qhg   = heads + szHD;
    _Float16* Khg   = Qhg + QKN;
    _Float16* Vtg   = Khg + QKN;
    // FF-phase view: ffbuf fp16 [TOK, FFx] (67MB) = heads..Vtg exactly
    _Float16* ffbuf = region;

    // weight planes (persistent, all layers, single fp16)
    _Float16* WqT = Vtg + QKN;
    _Float16* WkT = WqT + szQT;
    _Float16* WvT = WkT + szQT;
    _Float16* WoT = WvT + szQT;
    _Float16* W1c = WoT + szQT;
    _Float16* W2c = W1c + szW1;
    float*    part = (float*)(W2c + szW1);           // 128*1024 fp32 = 512 KB

    auto p32 = [](const void* p, size_t e) { return (const void*)((const float*)p + e); };
    auto p16 = [](const void* p, size_t e) { return (const void*)((const __hip_bfloat16*)p + e); };

    detect_kernel<<<1, 64, 0, stream>>>(x, dtp);

    // one-time weight conversion (fp16 single-plane, pre-transposed where needed)
    transpose_cvt_kernel<<<dim3(1, 8, 24), 256, 0, stream>>>(Wq, WqT, Dx, DKx, dtp);
    transpose_cvt_kernel<<<dim3(1, 8, 24), 256, 0, stream>>>(Wk, WkT, Dx, DKx, dtp);
    transpose_cvt_kernel<<<dim3(1, 8, 24), 256, 0, stream>>>(Wv, WvT, Dx, DKx, dtp);
    transpose_cvt_kernel<<<dim3(8, 8, 3), 256, 0, stream>>>(Wo, WoT, Dx, Dx, dtp);
    cvt_kernel<<<szW1 / 256, 256, 0, stream>>>(W1, W1c, dtp);
    cvt_kernel<<<szW1 / 256, 256, 0, stream>>>(W2, W2c, dtp);

    embed_kernel<<<TOK * Dx / 256, 256, 0, stream>>>(x, We, be, hh, hl, dtp);

    const dim3 gQKV(12, TOK / 128);                   // 1536 blocks
    const dim3 gWo(Dx / 128, TOK / 128);              // 512 blocks
    const dim3 gAttn(Nx / 64, Hx * Bx);               // 2048 blocks
    const dim3 gFF1(FFx / 128, TOK / 128);            // 2048 blocks
    const dim3 gFF2(Dx / 128, TOK / 128);             // 512 blocks
    const size_t partBytes = 128 * 1024 * sizeof(float);
    for (int l = 0; l < 3; ++l) {
        const size_t eQ = (size_t)l * szWqkvL;
        const size_t e1 = (size_t)l * FFx * Dx;
        const size_t eD = (size_t)l * Dx, eF = (size_t)l * FFx;
        const bool last = (l == 2);

        qkv_mfma<<<gQKV, 256, 0, stream>>>(
            hh, WqT + eQ, WkT + eQ, WvT + eQ,
            Qhg, Khg, Vtg, TOK, Dx);
        attn_kernel<<<gAttn, 256, 0, stream>>>(Qhg, Khg, Vtg, heads);

        // output projection + residual -> packed t ; fused stats
        hipMemsetAsync(part, 0, partBytes, stream);
        gemm3<2, 2, 1><<<gWo, 256, 0, stream>>>(
            heads, WoT + eQ,
            nullptr, nullptr, hh, hl, tpk, part, TOK, Dx, Dx, dtp);
        bn_final<<<4, 256, 0, stream>>>(part, stats);
        bn_norm<<<TOK * Dx / 256, 256, 0, stream>>>(
            tpk, stats, p32(g1, eD), p16(g1, eD), p32(b1, eD), p16(b1, eD),
            hh, hl, nullptr, dtp);

        // FF
        gemm3<1, 1, 0><<<gFF1, 256, 0, stream>>>(
            hh, W1c + e1,
            p32(bb1, eF), p16(bb1, eF), nullptr, nullptr, ffbuf, nullptr,
            TOK, FFx, Dx, dtp);
        hipMemsetAsync(part, 0, partBytes, stream);
        gemm3<2, 2, 1><<<gFF2, 256, 0, stream>>>(
            ffbuf, W2c + e1,
            p32(bb2, eD), p16(bb2, eD), hh, hl, tpk, part, TOK, Dx, FFx, dtp);
        bn_final<<<4, 256, 0, stream>>>(part, stats);
        bn_norm<<<TOK * Dx / 256, 256, 0, stream>>>(
            tpk, stats, p32(g2, eD), p16(g2, eD), p32(b2, eD), p16(b2, eD),
            hh, hl, last ? (float*)d_out : nullptr, dtp);
    }

    out_mean_part<<<dim3(Bx, 8), 256, 0, stream>>>(hh, hl, part);
    out_mean_final<<<Bx * Dx / 256, 256, 0, stream>>>(part, (float*)d_out + (size_t)TOK * Dx);
}